// Round 2
// 482.584 us; speedup vs baseline: 1.0009x; 1.0009x over previous
//
#include <hip/hip_runtime.h>

// SAMMCodebook.encode, round 5b: 2-phase double-buffered pipeline (stage t+1
// before compute t; single vmcnt(0)+barrier per K-step), non-temporal h loads
// (keep bf16 codebook L2-resident), XOR-swizzled LDS tiles (conflict-free
// ds_read_b128), and in-block exact fp32 fixup (no third kernel, no slots).
//
// z[n] = argmin_k (csq[k] - 2<h_n,c_k>). bf16 score error std ~0.1; DELTA=4
// (~40 sigma) margin guarantees the true argmin is among the candidates.

#define D_DIM 1024
#define K_CB  512
#define DELTA 4.0f
#define MAXC_IN 15            // stored "other" candidates; +1 best = 16 slots
#define FULLSCAN 0xFFFFu

typedef __attribute__((ext_vector_type(8))) short short8;
typedef __attribute__((ext_vector_type(4))) float floatx4;

// ws layout
#define WS_CBB  0ull           // 1 MB   cb bf16
#define WS_CSQ  1048576ull     // 2 KB   ||c||^2

typedef const unsigned int __attribute__((address_space(1)))* gaddr_t;
typedef unsigned int __attribute__((address_space(3)))* laddr_t;
static __device__ __forceinline__ void async_copy16(const void* g, void* l) {
    __builtin_amdgcn_global_load_lds((gaddr_t)g, (laddr_t)l, 16, 0, 0);
}

static __device__ __forceinline__ unsigned f2bf(float f) {
    unsigned u = __builtin_bit_cast(unsigned, f);
    return (u + 0x7FFFu + ((u >> 16) & 1u)) >> 16;   // round-nearest-even
}

// ---------------- cb fp32 -> bf16 + csq ----------------
__global__ __launch_bounds__(256)
void prep_kernel(const float* __restrict__ cb, unsigned short* __restrict__ cbb,
                 float* __restrict__ csq) {
    __shared__ float red[4];
    const int k = blockIdx.x, t = threadIdx.x;
    const float4 v = *(const float4*)(cb + (size_t)k * D_DIM + t * 4);
    uint2 u;
    u.x = f2bf(v.x) | (f2bf(v.y) << 16);
    u.y = f2bf(v.z) | (f2bf(v.w) << 16);
    *(uint2*)(cbb + (size_t)k * D_DIM + t * 4) = u;
    float s = v.x * v.x + v.y * v.y + v.z * v.z + v.w * v.w;
    #pragma unroll
    for (int off = 32; off > 0; off >>= 1) s += __shfl_down(s, off, 64);
    if ((t & 63) == 0) red[t >> 6] = s;
    __syncthreads();
    if (t == 0) csq[k] = red[0] + red[1] + red[2] + red[3];
}

// ---------------- coarse: 64x512 per block, pipelined, fused fixup ----------------
__global__ __launch_bounds__(256, 2)
void coarse_kernel(const float* __restrict__ h,
                   const unsigned short* __restrict__ cbb,
                   const float* __restrict__ csq,
                   const float* __restrict__ cb,
                   int* __restrict__ out) {
    // staging: As = 2 x [64][32] bf16 (8 KB), Bs = 2 x [512][32] bf16 (64 KB)
    // merge overlay (post-loop): mval[64][129] f32 | mcol[64][129] i32 | cand
    __shared__ unsigned char smem[73728] __attribute__((aligned(16)));
    unsigned short* As = (unsigned short*)smem;              // shorts
    unsigned short* Bs = (unsigned short*)(smem + 8192);

    const int tid = threadIdx.x;
    const int w = tid >> 6, lane = tid & 63;
    const int l15 = lane & 15, kq = lane >> 4;
    const size_t row0 = (size_t)blockIdx.x * 64;
    const int wc_ = w * 128;                 // wave's 128-col range

    // read-side swizzled 16B-slot offset (shorts), same for A and B reads:
    // rows are 16-aligned per tile so (row>>1)&3 == (l15>>1)&3
    const int qp8 = (kq ^ ((l15 >> 1) & 3)) * 8;

    // A staging: thread -> row tid>>2, logical slot tid&3 (8 floats)
    const int ar = tid >> 2, aql = tid & 3;
    const float* gA = h + (row0 + ar) * D_DIM + aql * 8;
    const int awoff = ar * 32 + (aql ^ ((ar >> 1) & 3)) * 8;  // swizzled write

    // B staging: physical LDS slot (row = j*64 + (tid>>2), qp = tid&3) pulls
    // global logical slot qsrc = qp ^ ((row>>1)&3) = (tid&3) ^ ((tid>>3)&3)
    const int qsrc = (tid & 3) ^ ((tid >> 3) & 3);
    const unsigned char* cbb_b = (const unsigned char*)cbb;
    const size_t bsrc0 = ((size_t)(tid >> 2) * D_DIM + qsrc * 8) * 2;  // bytes

    floatx4 acc[4][8];
    #pragma unroll
    for (int i = 0; i < 4; ++i)
        #pragma unroll
        for (int j = 0; j < 8; ++j) acc[i][j] = (floatx4){0.f, 0.f, 0.f, 0.f};

    // ---- prologue: stage step 0 into buffer 0 ----
    {
        const floatx4 va0 = __builtin_nontemporal_load((const floatx4*)gA);
        const floatx4 va1 = __builtin_nontemporal_load((const floatx4*)(gA + 4));
        #pragma unroll
        for (int j = 0; j < 8; ++j)
            async_copy16(cbb_b + bsrc0 + (size_t)j * 64 * D_DIM * 2,
                         Bs + (size_t)j * 2048 + w * 512);
        uint4 u;
        u.x = f2bf(va0.x) | (f2bf(va0.y) << 16);
        u.y = f2bf(va0.z) | (f2bf(va0.w) << 16);
        u.z = f2bf(va1.x) | (f2bf(va1.y) << 16);
        u.w = f2bf(va1.z) | (f2bf(va1.w) << 16);
        *(uint4*)(As + awoff) = u;
        __syncthreads();
    }

    // ---- 2-phase pipelined K-loop ----
    int cur = 0;
    for (int s = 0; s < 32; ++s) {
        floatx4 vb0, vb1;
        const int dn = (s + 1) * 32;
        if (s < 31) {
            // issue next-tile loads FIRST (A to regs, then B global->LDS);
            // waiting for A later = vmcnt(8), leaving B in flight over MFMA
            vb0 = __builtin_nontemporal_load((const floatx4*)(gA + dn));
            vb1 = __builtin_nontemporal_load((const floatx4*)(gA + dn + 4));
            #pragma unroll
            for (int j = 0; j < 8; ++j)
                async_copy16(cbb_b + bsrc0 + (size_t)j * 64 * D_DIM * 2 + (size_t)dn * 2,
                             Bs + (cur ^ 1) * 16384 + (size_t)j * 2048 + w * 512);
        }

        // compute on current buffer
        const unsigned short* Asc = As + cur * 2048;
        const unsigned short* Bsc = Bs + cur * 16384;
        short8 a[4], b[8];
        #pragma unroll
        for (int rt = 0; rt < 4; ++rt)
            a[rt] = *(const short8*)(Asc + (rt * 16 + l15) * 32 + qp8);
        #pragma unroll
        for (int ct = 0; ct < 8; ++ct)
            b[ct] = *(const short8*)(Bsc + (wc_ + ct * 16 + l15) * 32 + qp8);
        #pragma unroll
        for (int rt = 0; rt < 4; ++rt)
            #pragma unroll
            for (int ct = 0; ct < 8; ++ct)
                acc[rt][ct] = __builtin_amdgcn_mfma_f32_16x16x32_bf16(
                    a[rt], b[ct], acc[rt][ct], 0, 0, 0);

        if (s < 31) {
            uint4 u;
            u.x = f2bf(vb0.x) | (f2bf(vb0.y) << 16);
            u.y = f2bf(vb0.z) | (f2bf(vb0.w) << 16);
            u.z = f2bf(vb1.x) | (f2bf(vb1.y) << 16);
            u.w = f2bf(vb1.z) | (f2bf(vb1.w) << 16);
            *(uint4*)(As + (cur ^ 1) * 2048 + awoff) = u;
        }
        __syncthreads();    // drains vmcnt(0): B loads had the MFMA phase to land
        cur ^= 1;
    }

    // ---- fold: per-lane top-2 per row-reg (cell = 8 cols) ----
    float k1[16], k2[16];
    unsigned cpk[16];
    #pragma unroll
    for (int i = 0; i < 16; ++i) { k1[i] = 3.4e38f; k2[i] = 3.4e38f; cpk[i] = 0; }
    #pragma unroll
    for (int ct = 0; ct < 8; ++ct) {
        const int col = wc_ + ct * 16 + l15;
        const float cq = csq[col];
        #pragma unroll
        for (int rt = 0; rt < 4; ++rt)
            #pragma unroll
            for (int reg = 0; reg < 4; ++reg) {
                const float s = fmaf(-2.0f, acc[rt][ct][reg], cq);
                const int ri = rt * 4 + reg;
                if (s < k1[ri]) {
                    k2[ri] = k1[ri]; k1[ri] = s;
                    cpk[ri] = (cpk[ri] << 16) | (unsigned)col;
                } else if (s < k2[ri]) {
                    k2[ri] = s;
                    cpk[ri] = (cpk[ri] & 0xFFFFu) | ((unsigned)col << 16);
                }
            }
    }

    // ---- merge: 128 entries per row via LDS (stride 129: conflict-free scan) ----
    float* mval = (float*)smem;                        // [64][129]
    int*   mcol = (int*)(smem + 33024);                // [64][129]
    unsigned short* ccnt  = (unsigned short*)(smem + 66048);   // [64]
    unsigned short* clist = (unsigned short*)(smem + 66176);   // [64][16]
    __syncthreads();
    #pragma unroll
    for (int rt = 0; rt < 4; ++rt)
        #pragma unroll
        for (int reg = 0; reg < 4; ++reg) {
            const int ri = rt * 4 + reg;
            const int r = rt * 16 + kq * 4 + reg;
            const int e = (w * 16 + l15) * 2;
            mval[r * 129 + e] = k1[ri];
            mcol[r * 129 + e] = (int)(cpk[ri] & 0xFFFFu);
            mval[r * 129 + e + 1] = k2[ri];
            mcol[r * 129 + e + 1] = (int)(cpk[ri] >> 16);
        }
    __syncthreads();

    // ---- decide: best + candidate list per row ----
    if (tid < 64) {
        const int r = tid;
        float bv = mval[r * 129]; int bc = mcol[r * 129];
        for (int e = 1; e < 128; ++e) {
            const float v = mval[r * 129 + e];
            const int   c = mcol[r * 129 + e];
            if (v < bv || (v == bv && c < bc)) { bv = v; bc = c; }
        }
        const float thr = bv + DELTA;
        int others = 0;
        for (int e = 0; e < 128; ++e) {
            const float v = mval[r * 129 + e];
            const int   c = mcol[r * 129 + e];
            if (v < thr && c != bc) {
                if (others < MAXC_IN) clist[r * 16 + 1 + others] = (unsigned short)c;
                ++others;
            }
        }
        if (others == 0) {
            out[row0 + r] = bc;          // unambiguous: approx winner is exact
            ccnt[r] = 0;
        } else if (others <= MAXC_IN) {
            clist[r * 16] = (unsigned short)bc;
            ccnt[r] = (unsigned short)(others + 1);
        } else {
            ccnt[r] = (unsigned short)FULLSCAN;
        }
    }
    __syncthreads();

    // ---- in-block exact fp32 fixup: one wave per ambiguous row ----
    for (int r = w; r < 64; r += 4) {
        const unsigned cnt = ccnt[r];
        if (cnt == 0) continue;
        const size_t grow = row0 + r;
        const float* hrow = h + grow * D_DIM;
        float4 hv[4];
        #pragma unroll
        for (int j = 0; j < 4; ++j)
            hv[j] = *(const float4*)(hrow + j * 256 + lane * 4);
        float bs = 3.4e38f; int bc = 0x7fffffff;
        const bool full = (cnt == FULLSCAN);
        const int total = full ? K_CB : (int)cnt;
        for (int i = 0; i < total; ++i) {
            const int c = full ? i : (int)clist[r * 16 + i];
            const float* crow = cb + (size_t)c * D_DIM;
            float d = 0.0f;
            #pragma unroll
            for (int j = 0; j < 4; ++j) {
                const float4 cv = *(const float4*)(crow + j * 256 + lane * 4);
                d = fmaf(hv[j].x, cv.x, d);
                d = fmaf(hv[j].y, cv.y, d);
                d = fmaf(hv[j].z, cv.z, d);
                d = fmaf(hv[j].w, cv.w, d);
            }
            #pragma unroll
            for (int off = 32; off > 0; off >>= 1) d += __shfl_down(d, off, 64);
            d = __shfl(d, 0, 64);
            const float sc = fmaf(-2.0f, d, csq[c]);
            if (sc < bs || (sc == bs && c < bc)) { bs = sc; bc = c; }
        }
        if (lane == 0) out[grow] = bc;
    }
}

extern "C" void kernel_launch(void* const* d_in, const int* in_sizes, int n_in,
                              void* d_out, int out_size, void* d_ws, size_t ws_size,
                              hipStream_t stream) {
    const float* h  = (const float*)d_in[0];
    const float* cb = (const float*)d_in[1];
    int* out = (int*)d_out;
    unsigned char* ws = (unsigned char*)d_ws;
    const int nrows = in_sizes[0] / D_DIM;   // 65536

    unsigned short* cbb = (unsigned short*)(ws + WS_CBB);
    float* csq = (float*)(ws + WS_CSQ);

    prep_kernel<<<dim3(K_CB), dim3(256), 0, stream>>>(cb, cbb, csq);
    coarse_kernel<<<dim3(nrows / 64), dim3(256), 0, stream>>>(
        h, cbb, csq, cb, out);
}